// Round 7
// baseline (248.448 us; speedup 1.0000x reference)
//
#include <hip/hip_runtime.h>
#include <hip/hip_fp16.h>
#include <stdint.h>

#define N_NODES 50000
#define N_EDGES 800000
#define NB_SCAN ((N_NODES + 255) / 256)   // 196 blocks

// ---------------- CSR build ----------------

__global__ void count_kernel(const int* __restrict__ dst,
                             int* __restrict__ cnt, int e) {
    int i = blockIdx.x * blockDim.x + threadIdx.x;
    if (i < e) atomicAdd(&cnt[dst[i]], 1);
}

__global__ __launch_bounds__(256) void block_scan_kernel(
        const int* __restrict__ cnt, int* __restrict__ scanT,
        int* __restrict__ bsum, float* __restrict__ dinv, int n) {
    __shared__ int sh[256];
    int t = threadIdx.x;
    int i = blockIdx.x * 256 + t;
    int v = (i < n) ? cnt[i] : 0;
    if (i < n) dinv[i] = rsqrtf((float)(v + 1));  // +1 self-loop
    sh[t] = v;
    __syncthreads();
    for (int off = 1; off < 256; off <<= 1) {
        int u = (t >= off) ? sh[t - off] : 0;
        __syncthreads();
        sh[t] += u;
        __syncthreads();
    }
    if (i < n) scanT[i] = sh[t];
    if (t == 255) bsum[blockIdx.x] = sh[255];
}

__global__ __launch_bounds__(256) void bsum_scan_kernel(
        const int* __restrict__ bsum, int* __restrict__ boff, int nb) {
    __shared__ int sh[256];
    int t = threadIdx.x;
    sh[t] = (t < nb) ? bsum[t] : 0;
    __syncthreads();
    for (int off = 1; off < 256; off <<= 1) {
        int u = (t >= off) ? sh[t - off] : 0;
        __syncthreads();
        sh[t] += u;
        __syncthreads();
    }
    if (t < nb) boff[t] = (t == 0) ? 0 : sh[t - 1];
}

// writes rowptr AND a working copy for the fill atomics
__global__ __launch_bounds__(256) void rowptr_kernel(
        const int* __restrict__ scanT, const int* __restrict__ boff,
        int* __restrict__ rowptr, int* __restrict__ rp_work, int n) {
    int i = blockIdx.x * 256 + threadIdx.x;
    if (i < n) {
        int inc = scanT[i] + boff[blockIdx.x];   // inclusive scan at i
        rowptr[i + 1] = inc;
        if (i == 0) { rowptr[0] = 0; rp_work[0] = 0; }
        if (i + 1 < n) rp_work[i + 1] = inc;
    }
}

// one 8-B scattered write per edge: (src, dinv[src])
__global__ void fill_kernel(const int* __restrict__ src,
                            const int* __restrict__ dst,
                            int* __restrict__ rp_work,
                            const float* __restrict__ dinv,
                            int2* __restrict__ epack, int e) {
    int i = blockIdx.x * blockDim.x + threadIdx.x;
    if (i >= e) return;
    int s = src[i], d = dst[i];
    int pos = atomicAdd(&rp_work[d], 1);
    epack[pos] = make_int2(s, __float_as_int(dinv[s]));
}

// ---------------- tiled GEMM: out[n,C] = A[n,128] @ W[128,C] (+bias) ----------------

static __device__ __forceinline__ unsigned pack_h2(float a, float b) {
    __half2 h = __floats2half2_rn(a, b);
    return *reinterpret_cast<unsigned*>(&h);
}

template <int C, int BM, int RT, int CT, typename OutT>
__global__ __launch_bounds__(256, 4) void gemm_kernel(
        const float* __restrict__ A, const float* __restrict__ W,
        const float* __restrict__ bias, OutT* __restrict__ out, int n) {
    constexpr int KC = 32;
    constexpr int NCOLT = C / CT;
    constexpr int NROWT = BM / RT;
    static_assert(NCOLT * NROWT == 256, "bad tile");
    constexpr int PAD = BM + 4;
    constexpr int K4 = KC / 4;
    constexpr int XLOADS = (BM * K4) / 256;
    constexpr int WLOADS = (KC * C) / 1024;
    constexpr int NT = 128 / KC;

    __shared__ float xT[KC * PAD];
    __shared__ float Wl[KC * C];

    const int tid = threadIdx.x;
    const int colt = tid % NCOLT;
    const int rowt = tid / NCOLT;
    const int row0 = blockIdx.x * BM;

    float acc[RT][CT];
#pragma unroll
    for (int r = 0; r < RT; ++r)
#pragma unroll
        for (int c = 0; c < CT; ++c) acc[r][c] = 0.f;

    int xk4[XLOADS], xrow[XLOADS];
    const float* aptr[XLOADS];
#pragma unroll
    for (int i = 0; i < XLOADS; ++i) {
        int flat = tid + i * 256;
        xk4[i] = flat % K4;
        xrow[i] = flat / K4;
        int rg = row0 + xrow[i];
        if (rg > n - 1) rg = n - 1;
        aptr[i] = A + (size_t)rg * 128 + xk4[i] * 4;
    }
    float4 xr[XLOADS];
#pragma unroll
    for (int i = 0; i < XLOADS; ++i) xr[i] = *(const float4*)aptr[i];

    for (int t = 0; t < NT; ++t) {
#pragma unroll
        for (int i = 0; i < WLOADS; ++i) {
            int f4 = tid + i * 256;
            *(float4*)&Wl[f4 * 4] = *(const float4*)&W[t * KC * C + f4 * 4];
        }
#pragma unroll
        for (int i = 0; i < XLOADS; ++i) {
            xT[(xk4[i] * 4 + 0) * PAD + xrow[i]] = xr[i].x;
            xT[(xk4[i] * 4 + 1) * PAD + xrow[i]] = xr[i].y;
            xT[(xk4[i] * 4 + 2) * PAD + xrow[i]] = xr[i].z;
            xT[(xk4[i] * 4 + 3) * PAD + xrow[i]] = xr[i].w;
        }
        if (t < NT - 1) {
#pragma unroll
            for (int i = 0; i < XLOADS; ++i)
                xr[i] = *(const float4*)(aptr[i] + (t + 1) * KC);
        }
        __syncthreads();

#pragma unroll 2
        for (int kk = 0; kk < KC; ++kk) {
            float xv[RT], wv[CT];
            {
                const float* xb = &xT[kk * PAD + rowt * RT];
                float4 a = *(const float4*)xb;
                xv[0] = a.x; xv[1] = a.y; xv[2] = a.z; xv[3] = a.w;
                if constexpr (RT == 8) {
                    float4 b = *(const float4*)(xb + 4);
                    xv[4] = b.x; xv[5] = b.y; xv[6] = b.z; xv[7] = b.w;
                }
            }
            {
                const float* wb = &Wl[kk * C + colt * CT];
                float4 a = *(const float4*)wb;
                wv[0] = a.x; wv[1] = a.y; wv[2] = a.z; wv[3] = a.w;
                if constexpr (CT == 8) {
                    float4 b = *(const float4*)(wb + 4);
                    wv[4] = b.x; wv[5] = b.y; wv[6] = b.z; wv[7] = b.w;
                }
            }
#pragma unroll
            for (int r = 0; r < RT; ++r)
#pragma unroll
                for (int c = 0; c < CT; ++c)
                    acc[r][c] = fmaf(xv[r], wv[c], acc[r][c]);
        }
        __syncthreads();
    }

    float bv[CT];
#pragma unroll
    for (int c = 0; c < CT; ++c) bv[c] = bias ? bias[colt * CT + c] : 0.f;
#pragma unroll
    for (int r = 0; r < RT; ++r) {
        int rg = row0 + rowt * RT + r;
        if (rg < n) {
            OutT* op = &out[(size_t)rg * C + colt * CT];
            if constexpr (__hip_internal::is_same<OutT, __half>::value) {
                static_assert(CT == 8, "fp16 path assumes CT==8");
                uint4 u;
                u.x = pack_h2(acc[r][0] + bv[0], acc[r][1] + bv[1]);
                u.y = pack_h2(acc[r][2] + bv[2], acc[r][3] + bv[3]);
                u.z = pack_h2(acc[r][4] + bv[4], acc[r][5] + bv[5]);
                u.w = pack_h2(acc[r][6] + bv[6], acc[r][7] + bv[7]);
                *(uint4*)op = u;
            } else {
                float4 o0;
                o0.x = acc[r][0] + bv[0]; o0.y = acc[r][1] + bv[1];
                o0.z = acc[r][2] + bv[2]; o0.w = acc[r][3] + bv[3];
                *(float4*)op = o0;
                if constexpr (CT == 8) {
                    float4 o1;
                    o1.x = acc[r][4] + bv[4]; o1.y = acc[r][5] + bv[5];
                    o1.z = acc[r][6] + bv[6]; o1.w = acc[r][7] + bv[7];
                    *(float4*)(op + 4) = o1;
                }
            }
        }
    }
}

// ---------------- aggregation ----------------
// out[d] = dinv[d] * ( sum_e dinv[s_e]*t[s_e] + dinv[d]*t[d] ) + bias, relu
// fp16 messages, fp32 accumulate, 8 gathers in flight.

__global__ __launch_bounds__(256) void agg_kernel(
        const __half2* __restrict__ t, const int* __restrict__ rowptr,
        const int2* __restrict__ epack,
        const float* __restrict__ dinv, const float* __restrict__ bias,
        float* __restrict__ out, int n, int relu) {
    int wid = __builtin_amdgcn_readfirstlane((int)blockIdx.x * 4 + ((int)threadIdx.x >> 6));
    int lane = threadIdx.x & 63;
    if (wid >= n) return;
    int beg = rowptr[wid], end = rowptr[wid + 1];
    float di = dinv[wid];
    float2 sv = __half22float2(t[(size_t)wid * 64 + lane]);
    float ax0 = sv.x * di, ay0 = sv.y * di;   // self term: di*t[d] (outer di applied at end)
    float ax1 = 0.f, ay1 = 0.f, ax2 = 0.f, ay2 = 0.f, ax3 = 0.f, ay3 = 0.f;

    int e = beg;
    for (; e + 8 <= end; e += 8) {
        int2 e0 = epack[e],     e1 = epack[e + 1], e2 = epack[e + 2], e3 = epack[e + 3];
        int2 e4 = epack[e + 4], e5 = epack[e + 5], e6 = epack[e + 6], e7 = epack[e + 7];
        __half2 h0 = t[(size_t)e0.x * 64 + lane];
        __half2 h1 = t[(size_t)e1.x * 64 + lane];
        __half2 h2 = t[(size_t)e2.x * 64 + lane];
        __half2 h3 = t[(size_t)e3.x * 64 + lane];
        __half2 h4 = t[(size_t)e4.x * 64 + lane];
        __half2 h5 = t[(size_t)e5.x * 64 + lane];
        __half2 h6 = t[(size_t)e6.x * 64 + lane];
        __half2 h7 = t[(size_t)e7.x * 64 + lane];
        float2 v;
        v = __half22float2(h0); ax0 = fmaf(v.x, __int_as_float(e0.y), ax0); ay0 = fmaf(v.y, __int_as_float(e0.y), ay0);
        v = __half22float2(h1); ax1 = fmaf(v.x, __int_as_float(e1.y), ax1); ay1 = fmaf(v.y, __int_as_float(e1.y), ay1);
        v = __half22float2(h2); ax2 = fmaf(v.x, __int_as_float(e2.y), ax2); ay2 = fmaf(v.y, __int_as_float(e2.y), ay2);
        v = __half22float2(h3); ax3 = fmaf(v.x, __int_as_float(e3.y), ax3); ay3 = fmaf(v.y, __int_as_float(e3.y), ay3);
        v = __half22float2(h4); ax0 = fmaf(v.x, __int_as_float(e4.y), ax0); ay0 = fmaf(v.y, __int_as_float(e4.y), ay0);
        v = __half22float2(h5); ax1 = fmaf(v.x, __int_as_float(e5.y), ax1); ay1 = fmaf(v.y, __int_as_float(e5.y), ay1);
        v = __half22float2(h6); ax2 = fmaf(v.x, __int_as_float(e6.y), ax2); ay2 = fmaf(v.y, __int_as_float(e6.y), ay2);
        v = __half22float2(h7); ax3 = fmaf(v.x, __int_as_float(e7.y), ax3); ay3 = fmaf(v.y, __int_as_float(e7.y), ay3);
    }
    for (; e < end; ++e) {
        int2 ep = epack[e];
        float w = __int_as_float(ep.y);
        float2 v = __half22float2(t[(size_t)ep.x * 64 + lane]);
        ax0 = fmaf(v.x, w, ax0); ay0 = fmaf(v.y, w, ay0);
    }
    float ax = di * ((ax0 + ax1) + (ax2 + ax3));
    float ay = di * ((ay0 + ay1) + (ay2 + ay3));

    float2 b = ((const float2*)bias)[lane];
    ax += b.x; ay += b.y;
    if (relu) { ax = fmaxf(ax, 0.f); ay = fmaxf(ay, 0.f); }
    float2 o; o.x = ax; o.y = ay;
    ((float2*)out)[(size_t)wid * 64 + lane] = o;
}

// ---------------- launch ----------------

extern "C" void kernel_launch(void* const* d_in, const int* in_sizes, int n_in,
                              void* d_out, int out_size, void* d_ws, size_t ws_size,
                              hipStream_t stream) {
    const float* x  = (const float*)d_in[0];
    const int*   ei = (const int*)d_in[1];   // int64 in ref -> int32 on device
    const float* W1 = (const float*)d_in[2];
    const float* b1 = (const float*)d_in[3];
    const float* W2 = (const float*)d_in[4];
    const float* b2 = (const float*)d_in[5];
    const float* Wc = (const float*)d_in[6];
    const float* bc = (const float*)d_in[7];
    float*       out = (float*)d_out;

    const int n = N_NODES, e = N_EDGES;
    const int* srcp = ei;
    const int* dstp = ei + e;

    char* ws = (char*)d_ws;
    size_t off = 0;
    auto alloc = [&](size_t bytes) {
        void* p = ws + off;
        off += (bytes + 255) & ~(size_t)255;
        return p;
    };
    int*    cnt    = (int*)   alloc((size_t)n * 4);
    int*    scanT  = (int*)   alloc((size_t)n * 4);
    int*    bsum   = (int*)   alloc((size_t)NB_SCAN * 4);
    int*    boff   = (int*)   alloc((size_t)NB_SCAN * 4);
    int*    rowptr = (int*)   alloc((size_t)(n + 1) * 4);
    int*    rpwork = (int*)   alloc((size_t)n * 4);
    float*  dinv   = (float*) alloc((size_t)n * 4);
    int2*   epack  = (int2*)  alloc((size_t)e * 8);
    __half* bufT   = (__half*)alloc((size_t)n * 128 * 2);   // fp16 messages
    float*  bufH   = (float*) alloc((size_t)n * 128 * 4);

    hipMemsetAsync(cnt, 0, (size_t)n * 4, stream);

    count_kernel<<<(e + 255) / 256, 256, 0, stream>>>(dstp, cnt, e);
    block_scan_kernel<<<NB_SCAN, 256, 0, stream>>>(cnt, scanT, bsum, dinv, n);
    bsum_scan_kernel<<<1, 256, 0, stream>>>(bsum, boff, NB_SCAN);
    rowptr_kernel<<<NB_SCAN, 256, 0, stream>>>(scanT, boff, rowptr, rpwork, n);
    fill_kernel<<<(e + 255) / 256, 256, 0, stream>>>(srcp, dstp, rpwork, dinv, epack, e);

    const int gb = (n + 63) / 64;  // 782 blocks, ~3/CU

    // conv1: t = x @ W1 (fp16) ; h = relu(dinv*(agg) + b1) (fp32)
    gemm_kernel<128, 64, 4, 8, __half><<<gb, 256, 0, stream>>>(x, W1, nullptr, bufT, n);
    agg_kernel<<<(n + 3) / 4, 256, 0, stream>>>((const __half2*)bufT, rowptr, epack,
                                                dinv, b1, bufH, n, 1);
    // conv2
    gemm_kernel<128, 64, 4, 8, __half><<<gb, 256, 0, stream>>>(bufH, W2, nullptr, bufT, n);
    agg_kernel<<<(n + 3) / 4, 256, 0, stream>>>((const __half2*)bufT, rowptr, epack,
                                                dinv, b2, bufH, n, 1);
    // classifier: out = h @ Wc + bc (fp32)
    gemm_kernel<64, 64, 4, 4, float><<<gb, 256, 0, stream>>>(bufH, Wc, bc, out, n);
}

// Round 8
// 245.385 us; speedup vs baseline: 1.0125x; 1.0125x over previous
//
#include <hip/hip_runtime.h>
#include <hip/hip_fp16.h>
#include <stdint.h>

#define N_NODES 50000
#define N_EDGES 800000
#define NB_SCAN ((N_NODES + 255) / 256)   // 196 blocks

// ---------------- CSR build ----------------

// 4 edges/thread, fire-and-forget atomics
__global__ void count_kernel(const int4* __restrict__ dst4,
                             int* __restrict__ cnt, int e4) {
    int i = blockIdx.x * blockDim.x + threadIdx.x;
    if (i >= e4) return;
    int4 d = dst4[i];
    atomicAdd(&cnt[d.x], 1);
    atomicAdd(&cnt[d.y], 1);
    atomicAdd(&cnt[d.z], 1);
    atomicAdd(&cnt[d.w], 1);
}

__global__ __launch_bounds__(256) void block_scan_kernel(
        const int* __restrict__ cnt, int* __restrict__ scanT,
        int* __restrict__ bsum, float* __restrict__ dinv, int n) {
    __shared__ int sh[256];
    int t = threadIdx.x;
    int i = blockIdx.x * 256 + t;
    int v = (i < n) ? cnt[i] : 0;
    if (i < n) dinv[i] = rsqrtf((float)(v + 1));  // +1 self-loop
    sh[t] = v;
    __syncthreads();
    for (int off = 1; off < 256; off <<= 1) {
        int u = (t >= off) ? sh[t - off] : 0;
        __syncthreads();
        sh[t] += u;
        __syncthreads();
    }
    if (i < n) scanT[i] = sh[t];
    if (t == 255) bsum[blockIdx.x] = sh[255];
}

__global__ __launch_bounds__(256) void bsum_scan_kernel(
        const int* __restrict__ bsum, int* __restrict__ boff, int nb) {
    __shared__ int sh[256];
    int t = threadIdx.x;
    sh[t] = (t < nb) ? bsum[t] : 0;
    __syncthreads();
    for (int off = 1; off < 256; off <<= 1) {
        int u = (t >= off) ? sh[t - off] : 0;
        __syncthreads();
        sh[t] += u;
        __syncthreads();
    }
    if (t < nb) boff[t] = (t == 0) ? 0 : sh[t - 1];
}

// writes rowptr AND a working copy for the fill atomics
__global__ __launch_bounds__(256) void rowptr_kernel(
        const int* __restrict__ scanT, const int* __restrict__ boff,
        int* __restrict__ rowptr, int* __restrict__ rp_work, int n) {
    int i = blockIdx.x * 256 + threadIdx.x;
    if (i < n) {
        int inc = scanT[i] + boff[blockIdx.x];   // inclusive scan at i
        rowptr[i + 1] = inc;
        if (i == 0) { rowptr[0] = 0; rp_work[0] = 0; }
        if (i + 1 < n) rp_work[i + 1] = inc;
    }
}

// 4 edges/thread: 4 independent atomic->store chains in flight
__global__ void fill_kernel(const int4* __restrict__ src4,
                            const int4* __restrict__ dst4,
                            int* __restrict__ rp_work,
                            const float* __restrict__ dinv,
                            int2* __restrict__ epack, int e4) {
    int i = blockIdx.x * blockDim.x + threadIdx.x;
    if (i >= e4) return;
    int4 s = src4[i];
    int4 d = dst4[i];
    int p0 = atomicAdd(&rp_work[d.x], 1);
    int p1 = atomicAdd(&rp_work[d.y], 1);
    int p2 = atomicAdd(&rp_work[d.z], 1);
    int p3 = atomicAdd(&rp_work[d.w], 1);
    float f0 = dinv[s.x], f1 = dinv[s.y], f2 = dinv[s.z], f3 = dinv[s.w];
    epack[p0] = make_int2(s.x, __float_as_int(f0));
    epack[p1] = make_int2(s.y, __float_as_int(f1));
    epack[p2] = make_int2(s.z, __float_as_int(f2));
    epack[p3] = make_int2(s.w, __float_as_int(f3));
}

// ---------------- tiled GEMM: out[n,C] = A[n,128] @ W[128,C] (+bias) ----------------

static __device__ __forceinline__ unsigned pack_h2(float a, float b) {
    __half2 h = __floats2half2_rn(a, b);
    return *reinterpret_cast<unsigned*>(&h);
}

template <int C, int BM, int RT, int CT, typename OutT>
__global__ __launch_bounds__(256, 4) void gemm_kernel(
        const float* __restrict__ A, const float* __restrict__ W,
        const float* __restrict__ bias, OutT* __restrict__ out, int n) {
    constexpr int KC = 32;
    constexpr int NCOLT = C / CT;
    constexpr int NROWT = BM / RT;
    static_assert(NCOLT * NROWT == 256, "bad tile");
    constexpr int PAD = BM + 4;
    constexpr int K4 = KC / 4;
    constexpr int XLOADS = (BM * K4) / 256;
    constexpr int WLOADS = (KC * C) / 1024;
    constexpr int NT = 128 / KC;

    __shared__ float xT[KC * PAD];
    __shared__ float Wl[KC * C];

    const int tid = threadIdx.x;
    const int colt = tid % NCOLT;
    const int rowt = tid / NCOLT;
    const int row0 = blockIdx.x * BM;

    float acc[RT][CT];
#pragma unroll
    for (int r = 0; r < RT; ++r)
#pragma unroll
        for (int c = 0; c < CT; ++c) acc[r][c] = 0.f;

    int xk4[XLOADS], xrow[XLOADS];
    const float* aptr[XLOADS];
#pragma unroll
    for (int i = 0; i < XLOADS; ++i) {
        int flat = tid + i * 256;
        xk4[i] = flat % K4;
        xrow[i] = flat / K4;
        int rg = row0 + xrow[i];
        if (rg > n - 1) rg = n - 1;
        aptr[i] = A + (size_t)rg * 128 + xk4[i] * 4;
    }
    float4 xr[XLOADS];
#pragma unroll
    for (int i = 0; i < XLOADS; ++i) xr[i] = *(const float4*)aptr[i];

    for (int t = 0; t < NT; ++t) {
#pragma unroll
        for (int i = 0; i < WLOADS; ++i) {
            int f4 = tid + i * 256;
            *(float4*)&Wl[f4 * 4] = *(const float4*)&W[t * KC * C + f4 * 4];
        }
#pragma unroll
        for (int i = 0; i < XLOADS; ++i) {
            xT[(xk4[i] * 4 + 0) * PAD + xrow[i]] = xr[i].x;
            xT[(xk4[i] * 4 + 1) * PAD + xrow[i]] = xr[i].y;
            xT[(xk4[i] * 4 + 2) * PAD + xrow[i]] = xr[i].z;
            xT[(xk4[i] * 4 + 3) * PAD + xrow[i]] = xr[i].w;
        }
        if (t < NT - 1) {
#pragma unroll
            for (int i = 0; i < XLOADS; ++i)
                xr[i] = *(const float4*)(aptr[i] + (t + 1) * KC);
        }
        __syncthreads();

#pragma unroll 2
        for (int kk = 0; kk < KC; ++kk) {
            float xv[RT], wv[CT];
            {
                const float* xb = &xT[kk * PAD + rowt * RT];
                float4 a = *(const float4*)xb;
                xv[0] = a.x; xv[1] = a.y; xv[2] = a.z; xv[3] = a.w;
                if constexpr (RT == 8) {
                    float4 b = *(const float4*)(xb + 4);
                    xv[4] = b.x; xv[5] = b.y; xv[6] = b.z; xv[7] = b.w;
                }
            }
            {
                const float* wb = &Wl[kk * C + colt * CT];
                float4 a = *(const float4*)wb;
                wv[0] = a.x; wv[1] = a.y; wv[2] = a.z; wv[3] = a.w;
                if constexpr (CT == 8) {
                    float4 b = *(const float4*)(wb + 4);
                    wv[4] = b.x; wv[5] = b.y; wv[6] = b.z; wv[7] = b.w;
                }
            }
#pragma unroll
            for (int r = 0; r < RT; ++r)
#pragma unroll
                for (int c = 0; c < CT; ++c)
                    acc[r][c] = fmaf(xv[r], wv[c], acc[r][c]);
        }
        __syncthreads();
    }

    float bv[CT];
#pragma unroll
    for (int c = 0; c < CT; ++c) bv[c] = bias ? bias[colt * CT + c] : 0.f;
#pragma unroll
    for (int r = 0; r < RT; ++r) {
        int rg = row0 + rowt * RT + r;
        if (rg < n) {
            OutT* op = &out[(size_t)rg * C + colt * CT];
            if constexpr (__hip_internal::is_same<OutT, __half>::value) {
                static_assert(CT == 8, "fp16 path assumes CT==8");
                uint4 u;
                u.x = pack_h2(acc[r][0] + bv[0], acc[r][1] + bv[1]);
                u.y = pack_h2(acc[r][2] + bv[2], acc[r][3] + bv[3]);
                u.z = pack_h2(acc[r][4] + bv[4], acc[r][5] + bv[5]);
                u.w = pack_h2(acc[r][6] + bv[6], acc[r][7] + bv[7]);
                *(uint4*)op = u;
            } else {
                float4 o0;
                o0.x = acc[r][0] + bv[0]; o0.y = acc[r][1] + bv[1];
                o0.z = acc[r][2] + bv[2]; o0.w = acc[r][3] + bv[3];
                *(float4*)op = o0;
                if constexpr (CT == 8) {
                    float4 o1;
                    o1.x = acc[r][4] + bv[4]; o1.y = acc[r][5] + bv[5];
                    o1.z = acc[r][6] + bv[6]; o1.w = acc[r][7] + bv[7];
                    *(float4*)(op + 4) = o1;
                }
            }
        }
    }
}

// ---------------- aggregation ----------------
// out[d] = dinv[d] * ( sum_e dinv[s_e]*t[s_e] + dinv[d]*t[d] ) + bias, relu
// fp16 messages, fp32 accumulate, 8 gathers in flight.

__global__ __launch_bounds__(256) void agg_kernel(
        const __half2* __restrict__ t, const int* __restrict__ rowptr,
        const int2* __restrict__ epack,
        const float* __restrict__ dinv, const float* __restrict__ bias,
        float* __restrict__ out, int n, int relu) {
    int wid = __builtin_amdgcn_readfirstlane((int)blockIdx.x * 4 + ((int)threadIdx.x >> 6));
    int lane = threadIdx.x & 63;
    if (wid >= n) return;
    int beg = rowptr[wid], end = rowptr[wid + 1];
    float di = dinv[wid];
    float2 sv = __half22float2(t[(size_t)wid * 64 + lane]);
    float ax0 = sv.x * di, ay0 = sv.y * di;   // self term: di*t[d] (outer di applied at end)
    float ax1 = 0.f, ay1 = 0.f, ax2 = 0.f, ay2 = 0.f, ax3 = 0.f, ay3 = 0.f;

    int e = beg;
    for (; e + 8 <= end; e += 8) {
        int2 e0 = epack[e],     e1 = epack[e + 1], e2 = epack[e + 2], e3 = epack[e + 3];
        int2 e4 = epack[e + 4], e5 = epack[e + 5], e6 = epack[e + 6], e7 = epack[e + 7];
        __half2 h0 = t[(size_t)e0.x * 64 + lane];
        __half2 h1 = t[(size_t)e1.x * 64 + lane];
        __half2 h2 = t[(size_t)e2.x * 64 + lane];
        __half2 h3 = t[(size_t)e3.x * 64 + lane];
        __half2 h4 = t[(size_t)e4.x * 64 + lane];
        __half2 h5 = t[(size_t)e5.x * 64 + lane];
        __half2 h6 = t[(size_t)e6.x * 64 + lane];
        __half2 h7 = t[(size_t)e7.x * 64 + lane];
        float2 v;
        v = __half22float2(h0); ax0 = fmaf(v.x, __int_as_float(e0.y), ax0); ay0 = fmaf(v.y, __int_as_float(e0.y), ay0);
        v = __half22float2(h1); ax1 = fmaf(v.x, __int_as_float(e1.y), ax1); ay1 = fmaf(v.y, __int_as_float(e1.y), ay1);
        v = __half22float2(h2); ax2 = fmaf(v.x, __int_as_float(e2.y), ax2); ay2 = fmaf(v.y, __int_as_float(e2.y), ay2);
        v = __half22float2(h3); ax3 = fmaf(v.x, __int_as_float(e3.y), ax3); ay3 = fmaf(v.y, __int_as_float(e3.y), ay3);
        v = __half22float2(h4); ax0 = fmaf(v.x, __int_as_float(e4.y), ax0); ay0 = fmaf(v.y, __int_as_float(e4.y), ay0);
        v = __half22float2(h5); ax1 = fmaf(v.x, __int_as_float(e5.y), ax1); ay1 = fmaf(v.y, __int_as_float(e5.y), ay1);
        v = __half22float2(h6); ax2 = fmaf(v.x, __int_as_float(e6.y), ax2); ay2 = fmaf(v.y, __int_as_float(e6.y), ay2);
        v = __half22float2(h7); ax3 = fmaf(v.x, __int_as_float(e7.y), ax3); ay3 = fmaf(v.y, __int_as_float(e7.y), ay3);
    }
    for (; e < end; ++e) {
        int2 ep = epack[e];
        float w = __int_as_float(ep.y);
        float2 v = __half22float2(t[(size_t)ep.x * 64 + lane]);
        ax0 = fmaf(v.x, w, ax0); ay0 = fmaf(v.y, w, ay0);
    }
    float ax = di * ((ax0 + ax1) + (ax2 + ax3));
    float ay = di * ((ay0 + ay1) + (ay2 + ay3));

    float2 b = ((const float2*)bias)[lane];
    ax += b.x; ay += b.y;
    if (relu) { ax = fmaxf(ax, 0.f); ay = fmaxf(ay, 0.f); }
    float2 o; o.x = ax; o.y = ay;
    ((float2*)out)[(size_t)wid * 64 + lane] = o;
}

// ---------------- launch ----------------

extern "C" void kernel_launch(void* const* d_in, const int* in_sizes, int n_in,
                              void* d_out, int out_size, void* d_ws, size_t ws_size,
                              hipStream_t stream) {
    const float* x  = (const float*)d_in[0];
    const int*   ei = (const int*)d_in[1];   // int64 in ref -> int32 on device
    const float* W1 = (const float*)d_in[2];
    const float* b1 = (const float*)d_in[3];
    const float* W2 = (const float*)d_in[4];
    const float* b2 = (const float*)d_in[5];
    const float* Wc = (const float*)d_in[6];
    const float* bc = (const float*)d_in[7];
    float*       out = (float*)d_out;

    const int n = N_NODES, e = N_EDGES;
    const int e4 = e / 4;                     // 200000, exact
    const int* srcp = ei;
    const int* dstp = ei + e;

    char* ws = (char*)d_ws;
    size_t off = 0;
    auto alloc = [&](size_t bytes) {
        void* p = ws + off;
        off += (bytes + 255) & ~(size_t)255;
        return p;
    };
    int*    cnt    = (int*)   alloc((size_t)n * 4);
    int*    scanT  = (int*)   alloc((size_t)n * 4);
    int*    bsum   = (int*)   alloc((size_t)NB_SCAN * 4);
    int*    boff   = (int*)   alloc((size_t)NB_SCAN * 4);
    int*    rowptr = (int*)   alloc((size_t)(n + 1) * 4);
    int*    rpwork = (int*)   alloc((size_t)n * 4);
    float*  dinv   = (float*) alloc((size_t)n * 4);
    int2*   epack  = (int2*)  alloc((size_t)e * 8);
    __half* bufT   = (__half*)alloc((size_t)n * 128 * 2);   // fp16 messages
    float*  bufH   = (float*) alloc((size_t)n * 128 * 4);

    hipMemsetAsync(cnt, 0, (size_t)n * 4, stream);

    count_kernel<<<(e4 + 255) / 256, 256, 0, stream>>>((const int4*)dstp, cnt, e4);
    block_scan_kernel<<<NB_SCAN, 256, 0, stream>>>(cnt, scanT, bsum, dinv, n);
    bsum_scan_kernel<<<1, 256, 0, stream>>>(bsum, boff, NB_SCAN);
    rowptr_kernel<<<NB_SCAN, 256, 0, stream>>>(scanT, boff, rowptr, rpwork, n);
    fill_kernel<<<(e4 + 255) / 256, 256, 0, stream>>>((const int4*)srcp, (const int4*)dstp,
                                                      rpwork, dinv, epack, e4);

    const int gb = (n + 63) / 64;  // 782 blocks, ~3/CU

    // conv1: t = x @ W1 (fp16) ; h = relu(dinv*(agg) + b1) (fp32)
    gemm_kernel<128, 64, 4, 8, __half><<<gb, 256, 0, stream>>>(x, W1, nullptr, bufT, n);
    agg_kernel<<<(n + 3) / 4, 256, 0, stream>>>((const __half2*)bufT, rowptr, epack,
                                                dinv, b1, bufH, n, 1);
    // conv2
    gemm_kernel<128, 64, 4, 8, __half><<<gb, 256, 0, stream>>>(bufH, W2, nullptr, bufT, n);
    agg_kernel<<<(n + 3) / 4, 256, 0, stream>>>((const __half2*)bufT, rowptr, epack,
                                                dinv, b2, bufH, n, 1);
    // classifier: out = h @ Wc + bc (fp32)
    gemm_kernel<64, 64, 4, 4, float><<<gb, 256, 0, stream>>>(bufH, Wc, bc, out, n);
}

// Round 9
// 212.571 us; speedup vs baseline: 1.1688x; 1.1544x over previous
//
#include <hip/hip_runtime.h>
#include <hip/hip_fp16.h>
#include <stdint.h>

#define N_NODES 50000
#define N_EDGES 800000
#define NB_SCAN ((N_NODES + 255) / 256)   // 196 blocks

// ---------------- CSR build ----------------

// 4 edges/thread, fire-and-forget atomics
__global__ void count_kernel(const int4* __restrict__ dst4,
                             int* __restrict__ cnt, int e4) {
    int i = blockIdx.x * blockDim.x + threadIdx.x;
    if (i >= e4) return;
    int4 d = dst4[i];
    atomicAdd(&cnt[d.x], 1);
    atomicAdd(&cnt[d.y], 1);
    atomicAdd(&cnt[d.z], 1);
    atomicAdd(&cnt[d.w], 1);
}

__global__ __launch_bounds__(256) void block_scan_kernel(
        const int* __restrict__ cnt, int* __restrict__ scanT,
        int* __restrict__ bsum, float* __restrict__ dinv, int n) {
    __shared__ int sh[256];
    int t = threadIdx.x;
    int i = blockIdx.x * 256 + t;
    int v = (i < n) ? cnt[i] : 0;
    if (i < n) dinv[i] = rsqrtf((float)(v + 1));  // +1 self-loop
    sh[t] = v;
    __syncthreads();
    for (int off = 1; off < 256; off <<= 1) {
        int u = (t >= off) ? sh[t - off] : 0;
        __syncthreads();
        sh[t] += u;
        __syncthreads();
    }
    if (i < n) scanT[i] = sh[t];
    if (t == 255) bsum[blockIdx.x] = sh[255];
}

__global__ __launch_bounds__(256) void bsum_scan_kernel(
        const int* __restrict__ bsum, int* __restrict__ boff, int nb) {
    __shared__ int sh[256];
    int t = threadIdx.x;
    sh[t] = (t < nb) ? bsum[t] : 0;
    __syncthreads();
    for (int off = 1; off < 256; off <<= 1) {
        int u = (t >= off) ? sh[t - off] : 0;
        __syncthreads();
        sh[t] += u;
        __syncthreads();
    }
    if (t < nb) boff[t] = (t == 0) ? 0 : sh[t - 1];
}

// writes rowptr AND a working copy for the fill atomics
__global__ __launch_bounds__(256) void rowptr_kernel(
        const int* __restrict__ scanT, const int* __restrict__ boff,
        int* __restrict__ rowptr, int* __restrict__ rp_work, int n) {
    int i = blockIdx.x * 256 + threadIdx.x;
    if (i < n) {
        int inc = scanT[i] + boff[blockIdx.x];   // inclusive scan at i
        rowptr[i + 1] = inc;
        if (i == 0) { rowptr[0] = 0; rp_work[0] = 0; }
        if (i + 1 < n) rp_work[i + 1] = inc;
    }
}

// ---------------- fused fill + gemm1 ----------------
// Even blocks: CSR fill (latency-bound). Odd blocks: x@W1 tile (compute-bound).
// The CU scheduler co-resides both -> fill's fabric stalls hide under gemm VALU.

static __device__ __forceinline__ unsigned pack_h2(float a, float b) {
    __half2 h = __floats2half2_rn(a, b);
    return *reinterpret_cast<unsigned*>(&h);
}

template <int C, int BM, int RT, int CT, typename OutT>
static __device__ __forceinline__ void gemm_body(
        int bid, const float* __restrict__ A, const float* __restrict__ W,
        const float* __restrict__ bias, OutT* __restrict__ out, int n) {
    constexpr int KC = 32;
    constexpr int NCOLT = C / CT;
    constexpr int NROWT = BM / RT;
    static_assert(NCOLT * NROWT == 256, "bad tile");
    constexpr int PAD = BM + 4;
    constexpr int K4 = KC / 4;
    constexpr int XLOADS = (BM * K4) / 256;
    constexpr int WLOADS = (KC * C) / 1024;
    constexpr int NT = 128 / KC;

    __shared__ float xT[KC * PAD];
    __shared__ float Wl[KC * C];

    const int tid = threadIdx.x;
    const int colt = tid % NCOLT;
    const int rowt = tid / NCOLT;
    const int row0 = bid * BM;

    float acc[RT][CT];
#pragma unroll
    for (int r = 0; r < RT; ++r)
#pragma unroll
        for (int c = 0; c < CT; ++c) acc[r][c] = 0.f;

    int xk4[XLOADS], xrow[XLOADS];
    const float* aptr[XLOADS];
#pragma unroll
    for (int i = 0; i < XLOADS; ++i) {
        int flat = tid + i * 256;
        xk4[i] = flat % K4;
        xrow[i] = flat / K4;
        int rg = row0 + xrow[i];
        if (rg > n - 1) rg = n - 1;
        aptr[i] = A + (size_t)rg * 128 + xk4[i] * 4;
    }
    float4 xr[XLOADS];
#pragma unroll
    for (int i = 0; i < XLOADS; ++i) xr[i] = *(const float4*)aptr[i];

    for (int t = 0; t < NT; ++t) {
#pragma unroll
        for (int i = 0; i < WLOADS; ++i) {
            int f4 = tid + i * 256;
            *(float4*)&Wl[f4 * 4] = *(const float4*)&W[t * KC * C + f4 * 4];
        }
#pragma unroll
        for (int i = 0; i < XLOADS; ++i) {
            xT[(xk4[i] * 4 + 0) * PAD + xrow[i]] = xr[i].x;
            xT[(xk4[i] * 4 + 1) * PAD + xrow[i]] = xr[i].y;
            xT[(xk4[i] * 4 + 2) * PAD + xrow[i]] = xr[i].z;
            xT[(xk4[i] * 4 + 3) * PAD + xrow[i]] = xr[i].w;
        }
        if (t < NT - 1) {
#pragma unroll
            for (int i = 0; i < XLOADS; ++i)
                xr[i] = *(const float4*)(aptr[i] + (t + 1) * KC);
        }
        __syncthreads();

#pragma unroll 2
        for (int kk = 0; kk < KC; ++kk) {
            float xv[RT], wv[CT];
            {
                const float* xb = &xT[kk * PAD + rowt * RT];
                float4 a = *(const float4*)xb;
                xv[0] = a.x; xv[1] = a.y; xv[2] = a.z; xv[3] = a.w;
                if constexpr (RT == 8) {
                    float4 b = *(const float4*)(xb + 4);
                    xv[4] = b.x; xv[5] = b.y; xv[6] = b.z; xv[7] = b.w;
                }
            }
            {
                const float* wb = &Wl[kk * C + colt * CT];
                float4 a = *(const float4*)wb;
                wv[0] = a.x; wv[1] = a.y; wv[2] = a.z; wv[3] = a.w;
                if constexpr (CT == 8) {
                    float4 b = *(const float4*)(wb + 4);
                    wv[4] = b.x; wv[5] = b.y; wv[6] = b.z; wv[7] = b.w;
                }
            }
#pragma unroll
            for (int r = 0; r < RT; ++r)
#pragma unroll
                for (int c = 0; c < CT; ++c)
                    acc[r][c] = fmaf(xv[r], wv[c], acc[r][c]);
        }
        __syncthreads();
    }

    float bv[CT];
#pragma unroll
    for (int c = 0; c < CT; ++c) bv[c] = bias ? bias[colt * CT + c] : 0.f;
#pragma unroll
    for (int r = 0; r < RT; ++r) {
        int rg = row0 + rowt * RT + r;
        if (rg < n) {
            OutT* op = &out[(size_t)rg * C + colt * CT];
            if constexpr (__hip_internal::is_same<OutT, __half>::value) {
                static_assert(CT == 8, "fp16 path assumes CT==8");
                uint4 u;
                u.x = pack_h2(acc[r][0] + bv[0], acc[r][1] + bv[1]);
                u.y = pack_h2(acc[r][2] + bv[2], acc[r][3] + bv[3]);
                u.z = pack_h2(acc[r][4] + bv[4], acc[r][5] + bv[5]);
                u.w = pack_h2(acc[r][6] + bv[6], acc[r][7] + bv[7]);
                *(uint4*)op = u;
            } else {
                float4 o0;
                o0.x = acc[r][0] + bv[0]; o0.y = acc[r][1] + bv[1];
                o0.z = acc[r][2] + bv[2]; o0.w = acc[r][3] + bv[3];
                *(float4*)op = o0;
                if constexpr (CT == 8) {
                    float4 o1;
                    o1.x = acc[r][4] + bv[4]; o1.y = acc[r][5] + bv[5];
                    o1.z = acc[r][6] + bv[6]; o1.w = acc[r][7] + bv[7];
                    *(float4*)(op + 4) = o1;
                }
            }
        }
    }
}

static __device__ __forceinline__ void fill_body(
        int bid, const int4* __restrict__ src4, const int4* __restrict__ dst4,
        int* __restrict__ rp_work, const float* __restrict__ dinv,
        int2* __restrict__ epack, int e4) {
    int i = bid * 256 + threadIdx.x;
    if (i >= e4) return;
    int4 s = src4[i];
    int4 d = dst4[i];
    int p0 = atomicAdd(&rp_work[d.x], 1);
    int p1 = atomicAdd(&rp_work[d.y], 1);
    int p2 = atomicAdd(&rp_work[d.z], 1);
    int p3 = atomicAdd(&rp_work[d.w], 1);
    float f0 = dinv[s.x], f1 = dinv[s.y], f2 = dinv[s.z], f3 = dinv[s.w];
    epack[p0] = make_int2(s.x, __float_as_int(f0));
    epack[p1] = make_int2(s.y, __float_as_int(f1));
    epack[p2] = make_int2(s.z, __float_as_int(f2));
    epack[p3] = make_int2(s.w, __float_as_int(f3));
}

// nb_fill == nb_gemm == 782: even blocks fill, odd blocks gemm
__global__ __launch_bounds__(256, 4) void fill_gemm_kernel(
        const int4* __restrict__ src4, const int4* __restrict__ dst4,
        int* __restrict__ rp_work, const float* __restrict__ dinv,
        int2* __restrict__ epack, int e4,
        const float* __restrict__ A, const float* __restrict__ W,
        __half* __restrict__ out, int n) {
    int b = (int)blockIdx.x;
    if (b & 1) {
        gemm_body<128, 64, 4, 8, __half>(b >> 1, A, W, nullptr, out, n);
    } else {
        fill_body(b >> 1, src4, dst4, rp_work, dinv, epack, e4);
    }
}

// standalone gemm (conv2 + classifier)
template <int C, int BM, int RT, int CT, typename OutT>
__global__ __launch_bounds__(256, 4) void gemm_kernel(
        const float* __restrict__ A, const float* __restrict__ W,
        const float* __restrict__ bias, OutT* __restrict__ out, int n) {
    gemm_body<C, BM, RT, CT, OutT>((int)blockIdx.x, A, W, bias, out, n);
}

// ---------------- aggregation ----------------
// out[d] = dinv[d] * ( sum_e dinv[s_e]*t[s_e] + dinv[d]*t[d] ) + bias, relu
// fp16 messages, fp32 accumulate, 8 gathers in flight.

__global__ __launch_bounds__(256) void agg_kernel(
        const __half2* __restrict__ t, const int* __restrict__ rowptr,
        const int2* __restrict__ epack,
        const float* __restrict__ dinv, const float* __restrict__ bias,
        float* __restrict__ out, int n, int relu) {
    int wid = __builtin_amdgcn_readfirstlane((int)blockIdx.x * 4 + ((int)threadIdx.x >> 6));
    int lane = threadIdx.x & 63;
    if (wid >= n) return;
    int beg = rowptr[wid], end = rowptr[wid + 1];
    float di = dinv[wid];
    float2 sv = __half22float2(t[(size_t)wid * 64 + lane]);
    float ax0 = sv.x * di, ay0 = sv.y * di;   // self term (outer di applied at end)
    float ax1 = 0.f, ay1 = 0.f, ax2 = 0.f, ay2 = 0.f, ax3 = 0.f, ay3 = 0.f;

    int e = beg;
    for (; e + 8 <= end; e += 8) {
        int2 e0 = epack[e],     e1 = epack[e + 1], e2 = epack[e + 2], e3 = epack[e + 3];
        int2 e4 = epack[e + 4], e5 = epack[e + 5], e6 = epack[e + 6], e7 = epack[e + 7];
        __half2 h0 = t[(size_t)e0.x * 64 + lane];
        __half2 h1 = t[(size_t)e1.x * 64 + lane];
        __half2 h2 = t[(size_t)e2.x * 64 + lane];
        __half2 h3 = t[(size_t)e3.x * 64 + lane];
        __half2 h4 = t[(size_t)e4.x * 64 + lane];
        __half2 h5 = t[(size_t)e5.x * 64 + lane];
        __half2 h6 = t[(size_t)e6.x * 64 + lane];
        __half2 h7 = t[(size_t)e7.x * 64 + lane];
        float2 v;
        v = __half22float2(h0); ax0 = fmaf(v.x, __int_as_float(e0.y), ax0); ay0 = fmaf(v.y, __int_as_float(e0.y), ay0);
        v = __half22float2(h1); ax1 = fmaf(v.x, __int_as_float(e1.y), ax1); ay1 = fmaf(v.y, __int_as_float(e1.y), ay1);
        v = __half22float2(h2); ax2 = fmaf(v.x, __int_as_float(e2.y), ax2); ay2 = fmaf(v.y, __int_as_float(e2.y), ay2);
        v = __half22float2(h3); ax3 = fmaf(v.x, __int_as_float(e3.y), ax3); ay3 = fmaf(v.y, __int_as_float(e3.y), ay3);
        v = __half22float2(h4); ax0 = fmaf(v.x, __int_as_float(e4.y), ax0); ay0 = fmaf(v.y, __int_as_float(e4.y), ay0);
        v = __half22float2(h5); ax1 = fmaf(v.x, __int_as_float(e5.y), ax1); ay1 = fmaf(v.y, __int_as_float(e5.y), ay1);
        v = __half22float2(h6); ax2 = fmaf(v.x, __int_as_float(e6.y), ax2); ay2 = fmaf(v.y, __int_as_float(e6.y), ay2);
        v = __half22float2(h7); ax3 = fmaf(v.x, __int_as_float(e7.y), ax3); ay3 = fmaf(v.y, __int_as_float(e7.y), ay3);
    }
    for (; e < end; ++e) {
        int2 ep = epack[e];
        float w = __int_as_float(ep.y);
        float2 v = __half22float2(t[(size_t)ep.x * 64 + lane]);
        ax0 = fmaf(v.x, w, ax0); ay0 = fmaf(v.y, w, ay0);
    }
    float ax = di * ((ax0 + ax1) + (ax2 + ax3));
    float ay = di * ((ay0 + ay1) + (ay2 + ay3));

    float2 b = ((const float2*)bias)[lane];
    ax += b.x; ay += b.y;
    if (relu) { ax = fmaxf(ax, 0.f); ay = fmaxf(ay, 0.f); }
    float2 o; o.x = ax; o.y = ay;
    ((float2*)out)[(size_t)wid * 64 + lane] = o;
}

// ---------------- launch ----------------

extern "C" void kernel_launch(void* const* d_in, const int* in_sizes, int n_in,
                              void* d_out, int out_size, void* d_ws, size_t ws_size,
                              hipStream_t stream) {
    const float* x  = (const float*)d_in[0];
    const int*   ei = (const int*)d_in[1];   // int64 in ref -> int32 on device
    const float* W1 = (const float*)d_in[2];
    const float* b1 = (const float*)d_in[3];
    const float* W2 = (const float*)d_in[4];
    const float* b2 = (const float*)d_in[5];
    const float* Wc = (const float*)d_in[6];
    const float* bc = (const float*)d_in[7];
    float*       out = (float*)d_out;

    const int n = N_NODES, e = N_EDGES;
    const int e4 = e / 4;                     // 200000, exact
    const int* srcp = ei;
    const int* dstp = ei + e;

    char* ws = (char*)d_ws;
    size_t off = 0;
    auto alloc = [&](size_t bytes) {
        void* p = ws + off;
        off += (bytes + 255) & ~(size_t)255;
        return p;
    };
    int*    cnt    = (int*)   alloc((size_t)n * 4);
    int*    scanT  = (int*)   alloc((size_t)n * 4);
    int*    bsum   = (int*)   alloc((size_t)NB_SCAN * 4);
    int*    boff   = (int*)   alloc((size_t)NB_SCAN * 4);
    int*    rowptr = (int*)   alloc((size_t)(n + 1) * 4);
    int*    rpwork = (int*)   alloc((size_t)n * 4);
    float*  dinv   = (float*) alloc((size_t)n * 4);
    int2*   epack  = (int2*)  alloc((size_t)e * 8);
    __half* bufT   = (__half*)alloc((size_t)n * 128 * 2);   // fp16 messages
    float*  bufH   = (float*) alloc((size_t)n * 128 * 4);

    hipMemsetAsync(cnt, 0, (size_t)n * 4, stream);

    count_kernel<<<(e4 + 255) / 256, 256, 0, stream>>>((const int4*)dstp, cnt, e4);
    block_scan_kernel<<<NB_SCAN, 256, 0, stream>>>(cnt, scanT, bsum, dinv, n);
    bsum_scan_kernel<<<1, 256, 0, stream>>>(bsum, boff, NB_SCAN);
    rowptr_kernel<<<NB_SCAN, 256, 0, stream>>>(scanT, boff, rowptr, rpwork, n);

    const int nb_fill = (e4 + 255) / 256;     // 782
    const int nb_gemm = (n + 63) / 64;        // 782
    // fused: even blocks = fill, odd blocks = gemm1 (x@W1 -> fp16 bufT)
    fill_gemm_kernel<<<nb_fill + nb_gemm, 256, 0, stream>>>(
        (const int4*)srcp, (const int4*)dstp, rpwork, dinv, epack, e4,
        x, W1, bufT, n);

    agg_kernel<<<(n + 3) / 4, 256, 0, stream>>>((const __half2*)bufT, rowptr, epack,
                                                dinv, b1, bufH, n, 1);
    // conv2
    gemm_kernel<128, 64, 4, 8, __half><<<nb_gemm, 256, 0, stream>>>(bufH, W2, nullptr, bufT, n);
    agg_kernel<<<(n + 3) / 4, 256, 0, stream>>>((const __half2*)bufT, rowptr, epack,
                                                dinv, b2, bufH, n, 1);
    // classifier: out = h @ Wc + bc (fp32)
    gemm_kernel<64, 64, 4, 4, float><<<nb_gemm, 256, 0, stream>>>(bufH, Wc, bc, out, n);
}

// Round 10
// 201.379 us; speedup vs baseline: 1.2337x; 1.0556x over previous
//
#include <hip/hip_runtime.h>
#include <hip/hip_fp16.h>
#include <stdint.h>

#define N_NODES 50000
#define N_EDGES 800000
#define NB_SCAN ((N_NODES + 255) / 256)   // 196 blocks

typedef _Float16 half8 __attribute__((ext_vector_type(8)));
typedef float    f32x4 __attribute__((ext_vector_type(4)));

// ---------------- CSR build ----------------

__global__ void count_kernel(const int4* __restrict__ dst4,
                             int* __restrict__ cnt, int e4) {
    int i = blockIdx.x * blockDim.x + threadIdx.x;
    if (i >= e4) return;
    int4 d = dst4[i];
    atomicAdd(&cnt[d.x], 1);
    atomicAdd(&cnt[d.y], 1);
    atomicAdd(&cnt[d.z], 1);
    atomicAdd(&cnt[d.w], 1);
}

__global__ __launch_bounds__(256) void block_scan_kernel(
        const int* __restrict__ cnt, int* __restrict__ scanT,
        int* __restrict__ bsum, float* __restrict__ dinv, int n) {
    __shared__ int sh[256];
    int t = threadIdx.x;
    int i = blockIdx.x * 256 + t;
    int v = (i < n) ? cnt[i] : 0;
    if (i < n) dinv[i] = rsqrtf((float)(v + 1));  // +1 self-loop
    sh[t] = v;
    __syncthreads();
    for (int off = 1; off < 256; off <<= 1) {
        int u = (t >= off) ? sh[t - off] : 0;
        __syncthreads();
        sh[t] += u;
        __syncthreads();
    }
    if (i < n) scanT[i] = sh[t];
    if (t == 255) bsum[blockIdx.x] = sh[255];
}

__global__ __launch_bounds__(256) void bsum_scan_kernel(
        const int* __restrict__ bsum, int* __restrict__ boff, int nb) {
    __shared__ int sh[256];
    int t = threadIdx.x;
    sh[t] = (t < nb) ? bsum[t] : 0;
    __syncthreads();
    for (int off = 1; off < 256; off <<= 1) {
        int u = (t >= off) ? sh[t - off] : 0;
        __syncthreads();
        sh[t] += u;
        __syncthreads();
    }
    if (t < nb) boff[t] = (t == 0) ? 0 : sh[t - 1];
}

__global__ __launch_bounds__(256) void rowptr_kernel(
        const int* __restrict__ scanT, const int* __restrict__ boff,
        int* __restrict__ rowptr, int* __restrict__ rp_work, int n) {
    int i = blockIdx.x * 256 + threadIdx.x;
    if (i < n) {
        int inc = scanT[i] + boff[blockIdx.x];
        rowptr[i + 1] = inc;
        if (i == 0) { rowptr[0] = 0; rp_work[0] = 0; }
        if (i + 1 < n) rp_work[i + 1] = inc;
    }
}

// W2[128x128], Wc[128x64] -> fp16 transposed Bt[c][k]
__global__ __launch_bounds__(256) void convw_kernel(
        const float* __restrict__ W2, const float* __restrict__ Wc,
        _Float16* __restrict__ Bt2, _Float16* __restrict__ Btc) {
    int i = blockIdx.x * 256 + threadIdx.x;
    if (i < 128 * 128) {
        int c = i >> 7, k = i & 127;
        Bt2[i] = (_Float16)W2[k * 128 + c];
    } else {
        int j = i - 128 * 128;              // j < 64*128
        int c = j >> 7, k = j & 127;
        Btc[j] = (_Float16)Wc[k * 64 + c];
    }
}

// ---------------- fused fill + gemm1 (fp32 vector gemm, hidden under fill) ----------------

static __device__ __forceinline__ unsigned pack_h2(float a, float b) {
    __half2 h = __floats2half2_rn(a, b);
    return *reinterpret_cast<unsigned*>(&h);
}

template <int C, int BM, int RT, int CT>
static __device__ __forceinline__ void gemm_body(
        int bid, const float* __restrict__ A, const float* __restrict__ W,
        __half* __restrict__ out, int n) {
    constexpr int KC = 32;
    constexpr int NCOLT = C / CT;
    constexpr int PAD = BM + 4;
    constexpr int K4 = KC / 4;
    constexpr int XLOADS = (BM * K4) / 256;
    constexpr int WLOADS = (KC * C) / 1024;
    constexpr int NT = 128 / KC;

    __shared__ float xT[KC * PAD];
    __shared__ float Wl[KC * C];

    const int tid = threadIdx.x;
    const int colt = tid % NCOLT;
    const int rowt = tid / NCOLT;
    const int row0 = bid * BM;

    float acc[RT][CT];
#pragma unroll
    for (int r = 0; r < RT; ++r)
#pragma unroll
        for (int c = 0; c < CT; ++c) acc[r][c] = 0.f;

    int xk4[XLOADS], xrow[XLOADS];
    const float* aptr[XLOADS];
#pragma unroll
    for (int i = 0; i < XLOADS; ++i) {
        int flat = tid + i * 256;
        xk4[i] = flat % K4;
        xrow[i] = flat / K4;
        int rg = row0 + xrow[i];
        if (rg > n - 1) rg = n - 1;
        aptr[i] = A + (size_t)rg * 128 + xk4[i] * 4;
    }
    float4 xr[XLOADS];
#pragma unroll
    for (int i = 0; i < XLOADS; ++i) xr[i] = *(const float4*)aptr[i];

    for (int t = 0; t < NT; ++t) {
#pragma unroll
        for (int i = 0; i < WLOADS; ++i) {
            int f4 = tid + i * 256;
            *(float4*)&Wl[f4 * 4] = *(const float4*)&W[t * KC * C + f4 * 4];
        }
#pragma unroll
        for (int i = 0; i < XLOADS; ++i) {
            xT[(xk4[i] * 4 + 0) * PAD + xrow[i]] = xr[i].x;
            xT[(xk4[i] * 4 + 1) * PAD + xrow[i]] = xr[i].y;
            xT[(xk4[i] * 4 + 2) * PAD + xrow[i]] = xr[i].z;
            xT[(xk4[i] * 4 + 3) * PAD + xrow[i]] = xr[i].w;
        }
        if (t < NT - 1) {
#pragma unroll
            for (int i = 0; i < XLOADS; ++i)
                xr[i] = *(const float4*)(aptr[i] + (t + 1) * KC);
        }
        __syncthreads();

#pragma unroll 2
        for (int kk = 0; kk < KC; ++kk) {
            float xv[RT], wv[CT];
            {
                const float* xb = &xT[kk * PAD + rowt * RT];
                float4 a = *(const float4*)xb;
                xv[0] = a.x; xv[1] = a.y; xv[2] = a.z; xv[3] = a.w;
            }
            {
                const float* wb = &Wl[kk * C + colt * CT];
                float4 a = *(const float4*)wb;
                float4 b = *(const float4*)(wb + 4);
                wv[0] = a.x; wv[1] = a.y; wv[2] = a.z; wv[3] = a.w;
                wv[4] = b.x; wv[5] = b.y; wv[6] = b.z; wv[7] = b.w;
            }
#pragma unroll
            for (int r = 0; r < RT; ++r)
#pragma unroll
                for (int c = 0; c < CT; ++c)
                    acc[r][c] = fmaf(xv[r], wv[c], acc[r][c]);
        }
        __syncthreads();
    }

#pragma unroll
    for (int r = 0; r < RT; ++r) {
        int rg = row0 + rowt * RT + r;
        if (rg < n) {
            __half* op = &out[(size_t)rg * C + colt * CT];
            uint4 u;
            u.x = pack_h2(acc[r][0], acc[r][1]);
            u.y = pack_h2(acc[r][2], acc[r][3]);
            u.z = pack_h2(acc[r][4], acc[r][5]);
            u.w = pack_h2(acc[r][6], acc[r][7]);
            *(uint4*)op = u;
        }
    }
}

static __device__ __forceinline__ void fill_body(
        int bid, const int4* __restrict__ src4, const int4* __restrict__ dst4,
        int* __restrict__ rp_work, const float* __restrict__ dinv,
        int2* __restrict__ epack, int e4) {
    int i = bid * 256 + threadIdx.x;
    if (i >= e4) return;
    int4 s = src4[i];
    int4 d = dst4[i];
    int p0 = atomicAdd(&rp_work[d.x], 1);
    int p1 = atomicAdd(&rp_work[d.y], 1);
    int p2 = atomicAdd(&rp_work[d.z], 1);
    int p3 = atomicAdd(&rp_work[d.w], 1);
    float f0 = dinv[s.x], f1 = dinv[s.y], f2 = dinv[s.z], f3 = dinv[s.w];
    epack[p0] = make_int2(s.x, __float_as_int(f0));
    epack[p1] = make_int2(s.y, __float_as_int(f1));
    epack[p2] = make_int2(s.z, __float_as_int(f2));
    epack[p3] = make_int2(s.w, __float_as_int(f3));
}

// even blocks = fill, odd blocks = gemm1 (x@W1 -> fp16 bufT)
__global__ __launch_bounds__(256, 4) void fill_gemm_kernel(
        const int4* __restrict__ src4, const int4* __restrict__ dst4,
        int* __restrict__ rp_work, const float* __restrict__ dinv,
        int2* __restrict__ epack, int e4,
        const float* __restrict__ A, const float* __restrict__ W,
        __half* __restrict__ out, int n) {
    int b = (int)blockIdx.x;
    if (b & 1) {
        gemm_body<128, 64, 4, 8>(b >> 1, A, W, out, n);
    } else {
        fill_body(b >> 1, src4, dst4, rp_work, dinv, epack, e4);
    }
}

// ---------------- MFMA gemm: out[n,C] = A[n,128](fp16) @ Bt[C,128]^T (+bias) ----------------
// One wave = 16 rows x C cols. A/B frags loaded straight from global
// (16 rows x 64B segments, fully coalesced; Bt is L1/L2-resident).
// mfma_f32_16x16x32_f16: a[j] = A[m][hi*8+j], b[j] = B[hi*8+j][col],
// D[hi*4+r][col] = acc[r]  (m = col = lane&15, hi = lane>>4).

template <int C, bool BIAS, typename OutT>
__global__ __launch_bounds__(256) void mfma_gemm_kernel(
        const _Float16* __restrict__ A, const _Float16* __restrict__ Bt,
        const float* __restrict__ bias, OutT* __restrict__ out, int n) {
    constexpr int NT = C / 16;
    int wave = threadIdx.x >> 6;
    int lane = threadIdx.x & 63;
    int row0 = ((int)blockIdx.x * 4 + wave) * 16;
    if (row0 >= n) return;
    int m = lane & 15, hi = lane >> 4;

    half8 a[4];
    const _Float16* ap = A + (size_t)(row0 + m) * 128 + hi * 8;
#pragma unroll
    for (int k0 = 0; k0 < 4; ++k0) a[k0] = *(const half8*)(ap + k0 * 32);

#pragma unroll
    for (int nt = 0; nt < NT; ++nt) {
        f32x4 acc = {0.f, 0.f, 0.f, 0.f};
        const _Float16* bp = Bt + (size_t)(nt * 16 + m) * 128 + hi * 8;
#pragma unroll
        for (int k0 = 0; k0 < 4; ++k0) {
            half8 b = *(const half8*)(bp + k0 * 32);
            acc = __builtin_amdgcn_mfma_f32_16x16x32_f16(a[k0], b, acc, 0, 0, 0);
        }
        float bv = BIAS ? bias[nt * 16 + m] : 0.f;
#pragma unroll
        for (int r = 0; r < 4; ++r) {
            out[(size_t)(row0 + hi * 4 + r) * C + nt * 16 + m] = (OutT)(acc[r] + bv);
        }
    }
}

// ---------------- aggregation ----------------
// out[d] = fp16( dinv[d] * (sum_e dinv[s]*t[s] + dinv[d]*t[d]) + bias ), relu

__global__ __launch_bounds__(256) void agg_kernel(
        const __half2* __restrict__ t, const int* __restrict__ rowptr,
        const int2* __restrict__ epack,
        const float* __restrict__ dinv, const float* __restrict__ bias,
        __half2* __restrict__ out, int n) {
    int wid = __builtin_amdgcn_readfirstlane((int)blockIdx.x * 4 + ((int)threadIdx.x >> 6));
    int lane = threadIdx.x & 63;
    if (wid >= n) return;
    int beg = rowptr[wid], end = rowptr[wid + 1];
    float di = dinv[wid];
    float2 sv = __half22float2(t[(size_t)wid * 64 + lane]);
    float ax0 = sv.x * di, ay0 = sv.y * di;
    float ax1 = 0.f, ay1 = 0.f, ax2 = 0.f, ay2 = 0.f, ax3 = 0.f, ay3 = 0.f;

    int e = beg;
    for (; e + 8 <= end; e += 8) {
        int2 e0 = epack[e],     e1 = epack[e + 1], e2 = epack[e + 2], e3 = epack[e + 3];
        int2 e4 = epack[e + 4], e5 = epack[e + 5], e6 = epack[e + 6], e7 = epack[e + 7];
        __half2 h0 = t[(size_t)e0.x * 64 + lane];
        __half2 h1 = t[(size_t)e1.x * 64 + lane];
        __half2 h2 = t[(size_t)e2.x * 64 + lane];
        __half2 h3 = t[(size_t)e3.x * 64 + lane];
        __half2 h4 = t[(size_t)e4.x * 64 + lane];
        __half2 h5 = t[(size_t)e5.x * 64 + lane];
        __half2 h6 = t[(size_t)e6.x * 64 + lane];
        __half2 h7 = t[(size_t)e7.x * 64 + lane];
        float2 v;
        v = __half22float2(h0); ax0 = fmaf(v.x, __int_as_float(e0.y), ax0); ay0 = fmaf(v.y, __int_as_float(e0.y), ay0);
        v = __half22float2(h1); ax1 = fmaf(v.x, __int_as_float(e1.y), ax1); ay1 = fmaf(v.y, __int_as_float(e1.y), ay1);
        v = __half22float2(h2); ax2 = fmaf(v.x, __int_as_float(e2.y), ax2); ay2 = fmaf(v.y, __int_as_float(e2.y), ay2);
        v = __half22float2(h3); ax3 = fmaf(v.x, __int_as_float(e3.y), ax3); ay3 = fmaf(v.y, __int_as_float(e3.y), ay3);
        v = __half22float2(h4); ax0 = fmaf(v.x, __int_as_float(e4.y), ax0); ay0 = fmaf(v.y, __int_as_float(e4.y), ay0);
        v = __half22float2(h5); ax1 = fmaf(v.x, __int_as_float(e5.y), ax1); ay1 = fmaf(v.y, __int_as_float(e5.y), ay1);
        v = __half22float2(h6); ax2 = fmaf(v.x, __int_as_float(e6.y), ax2); ay2 = fmaf(v.y, __int_as_float(e6.y), ay2);
        v = __half22float2(h7); ax3 = fmaf(v.x, __int_as_float(e7.y), ax3); ay3 = fmaf(v.y, __int_as_float(e7.y), ay3);
    }
    for (; e < end; ++e) {
        int2 ep = epack[e];
        float w = __int_as_float(ep.y);
        float2 v = __half22float2(t[(size_t)ep.x * 64 + lane]);
        ax0 = fmaf(v.x, w, ax0); ay0 = fmaf(v.y, w, ay0);
    }
    float ax = di * ((ax0 + ax1) + (ax2 + ax3));
    float ay = di * ((ay0 + ay1) + (ay2 + ay3));

    float2 b = ((const float2*)bias)[lane];
    ax = fmaxf(ax + b.x, 0.f);
    ay = fmaxf(ay + b.y, 0.f);
    out[(size_t)wid * 64 + lane] = __floats2half2_rn(ax, ay);
}

// ---------------- launch ----------------

extern "C" void kernel_launch(void* const* d_in, const int* in_sizes, int n_in,
                              void* d_out, int out_size, void* d_ws, size_t ws_size,
                              hipStream_t stream) {
    const float* x  = (const float*)d_in[0];
    const int*   ei = (const int*)d_in[1];   // int64 in ref -> int32 on device
    const float* W1 = (const float*)d_in[2];
    const float* b1 = (const float*)d_in[3];
    const float* W2 = (const float*)d_in[4];
    const float* b2 = (const float*)d_in[5];
    const float* Wc = (const float*)d_in[6];
    const float* bc = (const float*)d_in[7];
    float*       out = (float*)d_out;

    const int n = N_NODES, e = N_EDGES;
    const int e4 = e / 4;                     // 200000, exact
    const int* srcp = ei;
    const int* dstp = ei + e;

    char* ws = (char*)d_ws;
    size_t off = 0;
    auto alloc = [&](size_t bytes) {
        void* p = ws + off;
        off += (bytes + 255) & ~(size_t)255;
        return p;
    };
    int*      cnt    = (int*)     alloc((size_t)n * 4);
    int*      scanT  = (int*)     alloc((size_t)n * 4);
    int*      bsum   = (int*)     alloc((size_t)NB_SCAN * 4);
    int*      boff   = (int*)     alloc((size_t)NB_SCAN * 4);
    int*      rowptr = (int*)     alloc((size_t)(n + 1) * 4);
    int*      rpwork = (int*)     alloc((size_t)n * 4);
    float*    dinv   = (float*)   alloc((size_t)n * 4);
    int2*     epack  = (int2*)    alloc((size_t)e * 8);
    __half*   bufT   = (__half*)  alloc((size_t)n * 128 * 2);  // fp16 messages
    _Float16* bufH   = (_Float16*)alloc((size_t)n * 128 * 2);  // fp16 h
    _Float16* Bt2    = (_Float16*)alloc((size_t)128 * 128 * 2);
    _Float16* Btc    = (_Float16*)alloc((size_t)64 * 128 * 2);

    hipMemsetAsync(cnt, 0, (size_t)n * 4, stream);

    convw_kernel<<<(128 * 128 + 64 * 128) / 256, 256, 0, stream>>>(W2, Wc, Bt2, Btc);
    count_kernel<<<(e4 + 255) / 256, 256, 0, stream>>>((const int4*)dstp, cnt, e4);
    block_scan_kernel<<<NB_SCAN, 256, 0, stream>>>(cnt, scanT, bsum, dinv, n);
    bsum_scan_kernel<<<1, 256, 0, stream>>>(bsum, boff, NB_SCAN);
    rowptr_kernel<<<NB_SCAN, 256, 0, stream>>>(scanT, boff, rowptr, rpwork, n);

    const int nb_fill = (e4 + 255) / 256;     // 782
    const int nb_gemm = (n + 63) / 64;        // 782
    fill_gemm_kernel<<<nb_fill + nb_gemm, 256, 0, stream>>>(
        (const int4*)srcp, (const int4*)dstp, rpwork, dinv, epack, e4,
        x, W1, bufT, n);

    // agg1 -> h (fp16)
    agg_kernel<<<(n + 3) / 4, 256, 0, stream>>>((const __half2*)bufT, rowptr, epack,
                                                dinv, b1, (__half2*)bufH, n);
    // conv2 gemm: t2 = h @ W2 (MFMA, fp16 out)
    const int nb_mfma = (n / 16 + 3) / 4;     // 782
    mfma_gemm_kernel<128, false, _Float16><<<nb_mfma, 256, 0, stream>>>(
        bufH, Bt2, nullptr, (_Float16*)bufT, n);
    // agg2 -> h2 (fp16)
    agg_kernel<<<(n + 3) / 4, 256, 0, stream>>>((const __half2*)bufT, rowptr, epack,
                                                dinv, b2, (__half2*)bufH, n);
    // classifier: out = h2 @ Wc + bc (MFMA, fp32 out)
    mfma_gemm_kernel<64, true, float><<<nb_mfma, 256, 0, stream>>>(
        bufH, Btc, bc, out, n);
}